// Round 2
// baseline (38374.756 us; speedup 1.0000x reference)
//
#include <hip/hip_runtime.h>

#define B 128
#define L 256
#define E 256
#define H 512

// ---- ws float offsets ----
#define WS_CTX   0u            // [B][L][H] = 16777216
#define WS_GPART 16777216u     // [6][2048][128] = 1572864
#define WS_HCAR  18350080u     // [H][B] h carry (recurrent h)
#define WS_HT    18415616u     // [H][B] lstm output h_t
#define WS_CST   18481152u     // [H][B] c state
#define WS_XT    18546688u     // [E][B] current x (transposed)
#define WS_INP   18579456u     // [B][H] inp = W_inp h_t + b
#define WS_HID   18644992u     // [H][B] attention context vector
#define WS_MASK  18710528u     // [B][L]

// ---- d_out float offsets ----
#define OUT_ALPHA 0u
#define OUT_PTR   8388608u
#define OUT_H     8421376u
#define OUT_C     8486912u

#define L2E 1.4426950408889634f

__device__ __forceinline__ float fast_rcp(float x) {
  return __builtin_amdgcn_rcpf(x);
}

__device__ __forceinline__ float fast_tanh(float x) {
  float a = fabsf(x);
  float t = exp2f(a * (-2.0f * L2E));
  float r = (1.0f - t) * fast_rcp(1.0f + t);
  return copysignf(r, x);
}

__device__ __forceinline__ float fast_sig(float x) {
  float a = fabsf(x);
  float t = exp2f(a * (-L2E));
  float r = fast_rcp(1.0f + t);
  return x >= 0.0f ? r : 1.0f - r;
}

// ================= precompute ctx[b][l][g] = sum_h context[b,l,h]*Wc[g,h] + bc[g]
__global__ __launch_bounds__(256) void k_ctx(const float* __restrict__ context,
                                             const float* __restrict__ Wc,
                                             const float* __restrict__ bc,
                                             float* __restrict__ ws) {
  __shared__ float a_lds[64][33];
  __shared__ float b_lds[32][68];
  int t = threadIdx.x;
  int m0 = blockIdx.x * 64;   // m = b*L + l  (M = 32768)
  int n0 = blockIdx.y * 64;   // n = g        (N = 512)
  int tx = t & 15, ty = t >> 4;
  float acc[4][4] = {};
  for (int kc = 0; kc < 16; ++kc) {
    int k0 = kc * 32;
    __syncthreads();
#pragma unroll
    for (int i = 0; i < 2; ++i) {
      int f4 = t + i * 256;          // 512 float4 slots
      int mm = f4 >> 3;
      int k4 = (f4 & 7) * 4;
      float4 v = *(const float4*)&context[(size_t)(m0 + mm) * H + k0 + k4];
      a_lds[mm][k4] = v.x; a_lds[mm][k4 + 1] = v.y; a_lds[mm][k4 + 2] = v.z; a_lds[mm][k4 + 3] = v.w;
    }
#pragma unroll
    for (int i = 0; i < 2; ++i) {
      int f4 = t + i * 256;          // 512 float4 slots -> 2048 floats (full 32x64 tile)
      int nn = f4 >> 3;              // 0..63
      int k4 = (f4 & 7) * 4;         // 0..28
      float4 v = *(const float4*)&Wc[(size_t)(n0 + nn) * H + k0 + k4];
      b_lds[k4][nn] = v.x; b_lds[k4 + 1][nn] = v.y; b_lds[k4 + 2][nn] = v.z; b_lds[k4 + 3][nn] = v.w;
    }
    __syncthreads();
#pragma unroll
    for (int kk = 0; kk < 32; ++kk) {
      float4 bv = *(const float4*)&b_lds[kk][tx * 4];
      float a0 = a_lds[ty * 4 + 0][kk], a1 = a_lds[ty * 4 + 1][kk];
      float a2 = a_lds[ty * 4 + 2][kk], a3 = a_lds[ty * 4 + 3][kk];
      acc[0][0] += a0 * bv.x; acc[0][1] += a0 * bv.y; acc[0][2] += a0 * bv.z; acc[0][3] += a0 * bv.w;
      acc[1][0] += a1 * bv.x; acc[1][1] += a1 * bv.y; acc[1][2] += a1 * bv.z; acc[1][3] += a1 * bv.w;
      acc[2][0] += a2 * bv.x; acc[2][1] += a2 * bv.y; acc[2][2] += a2 * bv.z; acc[2][3] += a2 * bv.w;
      acc[3][0] += a3 * bv.x; acc[3][1] += a3 * bv.y; acc[3][2] += a3 * bv.z; acc[3][3] += a3 * bv.w;
    }
  }
  float b0v = bc[n0 + tx * 4], b1v = bc[n0 + tx * 4 + 1], b2v = bc[n0 + tx * 4 + 2], b3v = bc[n0 + tx * 4 + 3];
#pragma unroll
  for (int i = 0; i < 4; ++i) {
    size_t o = WS_CTX + (size_t)(m0 + ty * 4 + i) * H + n0 + tx * 4;
    float4 v; v.x = acc[i][0] + b0v; v.y = acc[i][1] + b1v; v.z = acc[i][2] + b2v; v.w = acc[i][3] + b3v;
    *(float4*)&ws[o] = v;
  }
}

// ================= init state
__global__ __launch_bounds__(256) void k_init(const float* __restrict__ dec_h,
                                              const float* __restrict__ dec_c,
                                              const float* __restrict__ dec_in,
                                              float* __restrict__ ws) {
  int flat = blockIdx.x * 256 + threadIdx.x;
  if (flat < 65536) {
    int h = flat >> 7, b = flat & 127;
    ws[WS_HCAR + flat] = dec_h[(size_t)b * H + h];
  } else if (flat < 131072) {
    int f2 = flat - 65536;
    int h = f2 >> 7, b = f2 & 127;
    ws[WS_CST + f2] = dec_c[(size_t)b * H + h];
  } else if (flat < 163840) {
    int f2 = flat - 131072;
    int k = f2 >> 7, b = f2 & 127;
    ws[WS_XT + f2] = dec_in[(size_t)b * E + k];
  } else if (flat < 196608) {
    ws[WS_MASK + (flat - 163840)] = 1.0f;
  }
}

// ================= gates partials: gpart[ks][j][b] (split-K over 6 slices of 128)
__global__ __launch_bounds__(64) void k_gates(const float* __restrict__ Wi2h,
                                              const float* __restrict__ Wh2h,
                                              float* __restrict__ ws) {
  __shared__ float s_act[32][128];
  __shared__ float s_w[32][17];
  int t = threadIdx.x;
  int u0 = blockIdx.x * 4;
  int ks = blockIdx.y;
  const float* Wsrc; const float* act; int kbase, wK;
  if (ks < 2) { Wsrc = Wi2h; wK = E; kbase = ks * 128; act = ws + WS_XT; }
  else        { Wsrc = Wh2h; wK = H; kbase = (ks - 2) * 128; act = ws + WS_HCAR; }
  int bg = t & 15, rg = t >> 4;
  int b0 = bg * 8, r0 = rg * 4;
  float acc[4][8] = {};
  for (int ch = 0; ch < 4; ++ch) {
    int kb = kbase + ch * 32;
    __syncthreads();
#pragma unroll
    for (int i = 0; i < 16; ++i) {
      int f4 = t + i * 64;       // 1024 float4
      int kk = f4 >> 5, b4 = (f4 & 31) * 4;
      *(float4*)&s_act[kk][b4] = *(const float4*)&act[(size_t)(kb + kk) * B + b4];
    }
#pragma unroll
    for (int i = 0; i < 8; ++i) {
      int flat = t + i * 64;     // 512
      int kk = flat & 31, r = flat >> 5;
      int j = (r >> 2) * H + u0 + (r & 3);
      s_w[kk][r] = Wsrc[(size_t)j * wK + kb + kk];
    }
    __syncthreads();
#pragma unroll
    for (int kk = 0; kk < 32; ++kk) {
      float4 A0 = *(const float4*)&s_act[kk][b0];
      float4 A1 = *(const float4*)&s_act[kk][b0 + 4];
#pragma unroll
      for (int i = 0; i < 4; ++i) {
        float w = s_w[kk][r0 + i];
        acc[i][0] += w * A0.x; acc[i][1] += w * A0.y; acc[i][2] += w * A0.z; acc[i][3] += w * A0.w;
        acc[i][4] += w * A1.x; acc[i][5] += w * A1.y; acc[i][6] += w * A1.z; acc[i][7] += w * A1.w;
      }
    }
  }
#pragma unroll
  for (int i = 0; i < 4; ++i) {
    int r = r0 + i;
    int j = (r >> 2) * H + u0 + (r & 3);
    size_t base = WS_GPART + ((size_t)ks * 2048 + j) * B + b0;
    float4 p0; p0.x = acc[i][0]; p0.y = acc[i][1]; p0.z = acc[i][2]; p0.w = acc[i][3];
    float4 p1; p1.x = acc[i][4]; p1.y = acc[i][5]; p1.z = acc[i][6]; p1.w = acc[i][7];
    *(float4*)&ws[base] = p0;
    *(float4*)&ws[base + 4] = p1;
  }
}

// ================= reduce partials + LSTM elementwise
__global__ __launch_bounds__(256) void k_lstm(const float* __restrict__ bi,
                                              const float* __restrict__ bh,
                                              float* __restrict__ ws) {
  int flat = blockIdx.x * 256 + threadIdx.x;
  int u = flat >> 7, b = flat & 127;
  float s[4];
#pragma unroll
  for (int g = 0; g < 4; ++g) {
    int j = g * H + u;
    float a = bi[j] + bh[j];
    size_t base = WS_GPART + (size_t)j * B + b;
#pragma unroll
    for (int ks = 0; ks < 6; ++ks) a += ws[base + (size_t)ks * 2048 * B];
    s[g] = a;
  }
  size_t cb = WS_CST + (size_t)u * B + b;
  float c_old = ws[cb];
  float c_new = fast_sig(s[1]) * c_old + fast_sig(s[0]) * fast_tanh(s[2]);
  float h_t = fast_sig(s[3]) * fast_tanh(c_new);
  ws[cb] = c_new;
  ws[WS_HT + (size_t)u * B + b] = h_t;
}

// ================= inp[b][g] = W_inp h_t + b_inp
__global__ __launch_bounds__(256) void k_inp(const float* __restrict__ Wi,
                                             const float* __restrict__ bi,
                                             float* __restrict__ ws) {
  __shared__ float s_w[512][9];
  __shared__ float s_h[32][32];
  int t = threadIdx.x;
  int g0 = blockIdx.x * 8, b0 = blockIdx.y * 32;
#pragma unroll
  for (int i = 0; i < 16; ++i) {
    int flat = t + i * 256;
    int k = flat & 511, g = flat >> 9;
    s_w[k][g] = Wi[(size_t)(g0 + g) * H + k];
  }
  int bb = t & 31, dg = t >> 5;
  float acc = 0.f;
  for (int ch = 0; ch < 16; ++ch) {
    int kb = ch * 32;
    __syncthreads();
#pragma unroll
    for (int i = 0; i < 4; ++i) {
      int flat = t + i * 256;
      int kk = flat >> 5, b2 = flat & 31;
      s_h[kk][b2] = ws[WS_HT + (size_t)(kb + kk) * B + b0 + b2];
    }
    __syncthreads();
#pragma unroll
    for (int kk = 0; kk < 32; ++kk) acc += s_w[kb + kk][dg] * s_h[kk][bb];
  }
  ws[WS_INP + (size_t)(b0 + bb) * H + g0 + dg] = acc + bi[g0 + dg];
}

// ================= attention: scores -> softmax/argmax -> alpha out, x gather, hidden
__global__ __launch_bounds__(512) void k_attn(const float* __restrict__ Vv,
                                              const float* __restrict__ emb,
                                              float* __restrict__ ws,
                                              float* __restrict__ out,
                                              int step) {
  __shared__ float s_inp[512], s_v[512], s_mask[256], s_alpha[256];
  __shared__ float s_sc[256][2];
  __shared__ float s_red[4];
  __shared__ int s_redi[4];
  __shared__ float s_m, s_den;
  __shared__ int s_mi;
  int t = threadIdx.x;
  int b = blockIdx.x;
  s_inp[t] = ws[WS_INP + (size_t)b * H + t];
  s_v[t] = Vv[t];
  if (t < 256) s_mask[t] = ws[WS_MASK + (size_t)b * L + t];
  __syncthreads();
  // ---- scores (split g over 2 halves)
  {
    int l = t & 255, gh = t >> 8;
    float part = 0.f;
    if (s_mask[l] != 0.f) {
      size_t base = WS_CTX + ((size_t)b * L + l) * H + gh * 256;
      int gbase = gh * 256;
#pragma unroll 4
      for (int i = 0; i < 64; ++i) {
        float4 c4 = *(const float4*)&ws[base + i * 4];
        int g = gbase + i * 4;
        part += s_v[g]     * fast_tanh(s_inp[g]     + c4.x);
        part += s_v[g + 1] * fast_tanh(s_inp[g + 1] + c4.y);
        part += s_v[g + 2] * fast_tanh(s_inp[g + 2] + c4.z);
        part += s_v[g + 3] * fast_tanh(s_inp[g + 3] + c4.w);
      }
    }
    s_sc[l][gh] = part;
  }
  __syncthreads();
  float sc = 0.f;
  bool valid = false;
  if (t < 256) {
    sc = s_sc[t][0] + s_sc[t][1];
    valid = (s_mask[t] != 0.f);
    float bs = valid ? sc : -INFINITY;
    int bi = t;
#pragma unroll
    for (int off = 32; off > 0; off >>= 1) {
      float os = __shfl_down(bs, off);
      int oi = __shfl_down(bi, off);
      if (os > bs || (os == bs && oi < bi)) { bs = os; bi = oi; }
    }
    if ((t & 63) == 0) { s_red[t >> 6] = bs; s_redi[t >> 6] = bi; }
  }
  __syncthreads();
  if (t == 0) {
    float m = s_red[0]; int mi = s_redi[0];
#pragma unroll
    for (int w = 1; w < 4; ++w) {
      if (s_red[w] > m || (s_red[w] == m && s_redi[w] < mi)) { m = s_red[w]; mi = s_redi[w]; }
    }
    s_m = m; s_mi = mi;
  }
  __syncthreads();
  float e = 0.f;
  if (t < 256) {
    e = valid ? exp2f((sc - s_m) * L2E) : 0.f;
    float ssum = e;
#pragma unroll
    for (int off = 32; off > 0; off >>= 1) ssum += __shfl_down(ssum, off);
    if ((t & 63) == 0) s_red[t >> 6] = ssum;
  }
  __syncthreads();
  if (t == 0) s_den = s_red[0] + s_red[1] + s_red[2] + s_red[3];
  __syncthreads();
  int mi = s_mi;
  if (t < 256) {
    float alpha = e / s_den;
    s_alpha[t] = alpha;
    out[OUT_ALPHA + ((size_t)b * L + step) * L + t] = alpha;
    ws[WS_XT + (size_t)t * B + b] = emb[((size_t)b * L + mi) * E + t];
  }
  if (t == 0) {
    out[OUT_PTR + (size_t)b * L + step] = (float)mi;
    ws[WS_MASK + (size_t)b * L + mi] = 0.f;
  }
  __syncthreads();
  // ---- hidden[h] = sum_l alpha_l * ctx[b][l][h]   (t == h, 512 threads)
  {
    float acc = 0.f;
    for (int ll = 0; ll < 256; ++ll) {
      float al = s_alpha[ll];
      if (al != 0.f) acc += al * ws[WS_CTX + ((size_t)b * L + ll) * H + t];
    }
    ws[WS_HID + (size_t)t * B + b] = acc;
  }
}

// ================= h_new = tanh(W_out [hidden; h_t] + b_out) -> h carry
__global__ __launch_bounds__(256) void k_hnew(const float* __restrict__ Wo,
                                              const float* __restrict__ bo,
                                              float* __restrict__ ws) {
  __shared__ float s_w[1024][9];
  __shared__ float s_a[32][32];
  int t = threadIdx.x;
  int r0 = blockIdx.x * 8, b0 = blockIdx.y * 32;
#pragma unroll
  for (int i = 0; i < 32; ++i) {
    int flat = t + i * 256;
    int k = flat & 1023, r = flat >> 10;
    s_w[k][r] = Wo[(size_t)(r0 + r) * 1024 + k];
  }
  int bb = t & 31, dr = t >> 5;
  float acc = 0.f;
  for (int ch = 0; ch < 32; ++ch) {
    int kb = ch * 32;
    __syncthreads();
#pragma unroll
    for (int i = 0; i < 4; ++i) {
      int flat = t + i * 256;
      int kk = flat >> 5, b2 = flat & 31;
      int k = kb + kk;
      s_a[kk][b2] = (k < H) ? ws[WS_HID + (size_t)k * B + b0 + b2]
                            : ws[WS_HT + (size_t)(k - H) * B + b0 + b2];
    }
    __syncthreads();
#pragma unroll
    for (int kk = 0; kk < 32; ++kk) acc += s_w[kb + kk][dr] * s_a[kk][bb];
  }
  float hv = fast_tanh(acc + bo[r0 + dr]);
  ws[WS_HCAR + (size_t)(r0 + dr) * B + b0 + bb] = hv;
}

// ================= final h/c copy-out
__global__ __launch_bounds__(256) void k_end(const float* __restrict__ ws,
                                             float* __restrict__ out) {
  int flat = blockIdx.x * 256 + threadIdx.x;
  if (flat < 65536) {
    int b = flat >> 9, h = flat & 511;
    out[OUT_H + flat] = ws[WS_HCAR + (size_t)h * B + b];
  } else {
    int f2 = flat - 65536;
    int b = f2 >> 9, h = f2 & 511;
    out[OUT_C + f2] = ws[WS_CST + (size_t)h * B + b];
  }
}

extern "C" void kernel_launch(void* const* d_in, const int* in_sizes, int n_in,
                              void* d_out, int out_size, void* d_ws, size_t ws_size,
                              hipStream_t stream) {
  (void)in_sizes; (void)n_in; (void)out_size; (void)ws_size;
  const float* emb    = (const float*)d_in[0];
  const float* dec_in = (const float*)d_in[1];
  const float* dec_h  = (const float*)d_in[2];
  const float* dec_c  = (const float*)d_in[3];
  const float* ctx_in = (const float*)d_in[4];
  const float* W_i2h  = (const float*)d_in[5];
  const float* b_i2h  = (const float*)d_in[6];
  const float* W_h2h  = (const float*)d_in[7];
  const float* b_h2h  = (const float*)d_in[8];
  const float* W_out  = (const float*)d_in[9];
  const float* b_out  = (const float*)d_in[10];
  const float* W_inp  = (const float*)d_in[11];
  const float* b_inp  = (const float*)d_in[12];
  const float* W_ctx  = (const float*)d_in[13];
  const float* b_ctx  = (const float*)d_in[14];
  const float* Vv     = (const float*)d_in[15];
  float* out = (float*)d_out;
  float* ws  = (float*)d_ws;

  k_ctx<<<dim3(512, 8), 256, 0, stream>>>(ctx_in, W_ctx, b_ctx, ws);
  k_init<<<768, 256, 0, stream>>>(dec_h, dec_c, dec_in, ws);

  for (int step = 0; step < L; ++step) {
    k_gates<<<dim3(128, 6), 64, 0, stream>>>(W_i2h, W_h2h, ws);
    k_lstm<<<256, 256, 0, stream>>>(b_i2h, b_h2h, ws);
    k_inp<<<dim3(64, 4), 256, 0, stream>>>(W_inp, b_inp, ws);
    k_attn<<<128, 512, 0, stream>>>(Vv, emb, ws, out, step);
    k_hnew<<<dim3(64, 4), 256, 0, stream>>>(W_out, b_out, ws);
  }
  k_end<<<512, 256, 0, stream>>>(ws, out);
}